// Round 3
// baseline (790.062 us; speedup 1.0000x reference)
//
#include <hip/hip_runtime.h>

// Register-resident fused-8 Jacobi. Thread = fixed 4x4 patch in VGPRs; weights
// (iteration-invariant, kappa-derived) precomputed once; per-step halo exchange
// via double-buffered LDS edge buffers (1 barrier/step, conflict-free b128).
// No per-step masking: trapezoid validity + zeroed out-of-domain weights.

namespace {
constexpr int    G    = 1024, Ni = 1022;
constexpr int    TOUT = 48, HALO = 8;
constexpr int    KSTR = 68;                       // kT row stride (16B-aligned rows)
constexpr size_t IMG_K = (size_t)G * G;
constexpr size_t IMG_P = (size_t)Ni * Ni;
constexpr size_t WSTR  = 1024;
constexpr size_t IMG_W = (size_t)1024 * 1024;     // ws image incl. zero pad rows/cols
constexpr float  H2 = (float)(1.0 / (1023.0 * 1023.0));
// LDS: setup kT[66*68]=4488 | fT[64*64]=4096  (8584 floats total)
// main: exchange dbuf = 2 * 4096 floats, overlays setup region. 34,336 B.
}

__device__ __forceinline__ float frcp(float x) { return __builtin_amdgcn_rcpf(x); }

template<bool FIRST, bool LAST>
__global__ __launch_bounds__(256, 4)
void jac_fused8(const float* __restrict__ usrc, float* __restrict__ udst,
                const float* __restrict__ kap,  const float* __restrict__ fin)
{
    __shared__ float lds[8584];
    float* kT = lds;                 // 66 rows x 68 stride
    float* fT = lds + 4488;          // 64 x 64

    const int tid = threadIdx.x;
    const int pr = tid >> 4, pc = tid & 15;
    const int R0 = pr * 4, C0 = pc * 4;
    const int bx = blockIdx.x, by = blockIdx.y, b = blockIdx.z;
    const int X0 = bx * TOUT - HALO, Y0 = by * TOUT - HALO;

    const float* kB = kap + (size_t)b * IMG_K;
    const float* fB = fin + (size_t)b * IMG_K;

    // ---- u patch into registers ----
    float u[4][4];
    if (FIRST) {
        const float* uS = usrc + (size_t)b * IMG_P;       // pre, stride 1022
        #pragma unroll
        for (int dr = 0; dr < 4; ++dr) {
            const int gy = Y0 + R0 + dr;
            #pragma unroll
            for (int dc = 0; dc < 4; ++dc) {
                const int gx = X0 + C0 + dc;
                u[dr][dc] = ((unsigned)gy < (unsigned)Ni && (unsigned)gx < (unsigned)Ni)
                          ? uS[(size_t)gy * Ni + gx] : 0.0f;
            }
        }
    } else {
        const float* uS = usrc + (size_t)b * IMG_W;       // ws, stride 1024, padded
        const int gx = X0 + C0;
        #pragma unroll
        for (int dr = 0; dr < 4; ++dr) {
            const int gy = Y0 + R0 + dr;
            float4 v = make_float4(0.f, 0.f, 0.f, 0.f);
            if ((unsigned)gy < 1024u && (unsigned)gx <= 1020u)
                v = *(const float4*)(uS + (size_t)gy * WSTR + gx);
            u[dr][0] = v.x; u[dr][1] = v.y; u[dr][2] = v.z; u[dr][3] = v.w;
        }
    }

    // ---- stage kappa tile (grid [Y0,Y0+66) x [X0,X0+66), clipped) ----
    for (int lin = tid; lin < 66 * 66; lin += 256) {
        const int r = lin / 66, c = lin - r * 66;
        const int gy = Y0 + r, gx = X0 + c;
        float v = 0.0f;
        if ((unsigned)gy < (unsigned)G && (unsigned)gx < (unsigned)G)
            v = kB[(size_t)gy * G + gx];
        kT[r * KSTR + c] = v;
    }
    // ---- stage f tile (f grid (Y0+r+1, X0+c+1), clipped) ----
    #pragma unroll
    for (int k = 0; k < 16; ++k) {
        const int lin = tid + k * 256;
        const int r = lin >> 6, c = lin & 63;
        const int gy = Y0 + r + 1, gx = X0 + c + 1;
        float v = 0.0f;
        if ((unsigned)gy < (unsigned)G && (unsigned)gx < (unsigned)G)
            v = fB[(size_t)gy * G + gx];
        fT[r * 64 + c] = v;
    }
    __syncthreads();

    // ---- iteration-invariant weights (zeroed outside domain) ----
    float wN[4][4], wS[4][4], wW[4][4], wE[4][4], Fc[4][4];
    {
        float ka[6], kb2[6], kc2[6];
        auto loadK = [&](int r, float* dst) {
            const float4 q = *(const float4*)(kT + r * KSTR + C0);
            const float2 p = *(const float2*)(kT + r * KSTR + C0 + 4);
            dst[0] = q.x; dst[1] = q.y; dst[2] = q.z; dst[3] = q.w; dst[4] = p.x; dst[5] = p.y;
        };
        loadK(R0 + 0, ka);
        loadK(R0 + 1, kb2);
        #pragma unroll
        for (int dr = 0; dr < 4; ++dr) {
            loadK(R0 + dr + 2, kc2);
            const float4 fr = *(const float4*)(fT + (R0 + dr) * 64 + C0);
            const float frow[4] = {fr.x, fr.y, fr.z, fr.w};
            const int gy = Y0 + R0 + dr;
            #pragma unroll
            for (int dc = 0; dc < 4; ++dc) {
                const float kn = ka[dc + 1], kc = kb2[dc + 1], kw = kb2[dc],
                            ke = kb2[dc + 2], ks = kc2[dc + 1];
                const float y3  = 2.0f * kc + 0.5f * (kn + ks + kw + ke);
                const float inv = frcp(y3);
                const int gx = X0 + C0 + dc;
                const bool dv = ((unsigned)gy < (unsigned)Ni) && ((unsigned)gx < (unsigned)Ni);
                wN[dr][dc] = dv ? 0.5f * (kc + kn) * inv : 0.0f;
                wS[dr][dc] = dv ? 0.5f * (kc + ks) * inv : 0.0f;
                wW[dr][dc] = dv ? 0.5f * (kc + kw) * inv : 0.0f;
                wE[dr][dc] = dv ? 0.5f * (kc + ke) * inv : 0.0f;
                Fc[dr][dc] = dv ? frow[dc] * H2 * inv : 0.0f;
            }
            #pragma unroll
            for (int i = 0; i < 6; ++i) { ka[i] = kb2[i]; kb2[i] = kc2[i]; }
        }
    }
    __syncthreads();   // kT/fT dead; exchange buffers overlay them

    // ---- 8 Jacobi steps, halo via dbuf LDS edge exchange ----
    const int tN = (tid >= 16)  ? tid - 16 : 0;
    const int tS = (tid < 240)  ? tid + 16 : 255;
    const int tW = (tid > 0)    ? tid - 1  : 0;
    const int tE = (tid < 255)  ? tid + 1  : 255;

    #pragma unroll
    for (int t = 1; t <= 8; ++t) {
        float* ex   = lds + ((t & 1) ? 0 : 4096);
        float* rowT = ex, *rowB = ex + 1024, *colL = ex + 2048, *colR = ex + 3072;
        *(float4*)(rowT + tid * 4) = make_float4(u[0][0], u[0][1], u[0][2], u[0][3]);
        *(float4*)(rowB + tid * 4) = make_float4(u[3][0], u[3][1], u[3][2], u[3][3]);
        *(float4*)(colL + tid * 4) = make_float4(u[0][0], u[1][0], u[2][0], u[3][0]);
        *(float4*)(colR + tid * 4) = make_float4(u[0][3], u[1][3], u[2][3], u[3][3]);
        __syncthreads();
        const float4 hN = *(const float4*)(rowB + tN * 4);
        const float4 hS = *(const float4*)(rowT + tS * 4);
        const float4 hW = *(const float4*)(colR + tW * 4);
        const float4 hE = *(const float4*)(colL + tE * 4);
        float pn[4]        = {hN.x, hN.y, hN.z, hN.w};
        const float hWv[4] = {hW.x, hW.y, hW.z, hW.w};
        const float hEv[4] = {hE.x, hE.y, hE.z, hE.w};
        #pragma unroll
        for (int dr = 0; dr < 4; ++dr) {
            float so0, so1, so2, so3;
            if (dr < 3) { so0 = u[dr+1][0]; so1 = u[dr+1][1]; so2 = u[dr+1][2]; so3 = u[dr+1][3]; }
            else        { so0 = hS.x;       so1 = hS.y;       so2 = hS.z;       so3 = hS.w;       }
            const float o0 = u[dr][0], o1 = u[dr][1], o2 = u[dr][2], o3 = u[dr][3];
            u[dr][0] = fmaf(wE[dr][0], o1,
                       fmaf(wW[dr][0], hWv[dr],
                       fmaf(wS[dr][0], so0,
                       fmaf(wN[dr][0], pn[0], Fc[dr][0]))));
            u[dr][1] = fmaf(wE[dr][1], o2,
                       fmaf(wW[dr][1], o0,
                       fmaf(wS[dr][1], so1,
                       fmaf(wN[dr][1], pn[1], Fc[dr][1]))));
            u[dr][2] = fmaf(wE[dr][2], o3,
                       fmaf(wW[dr][2], o1,
                       fmaf(wS[dr][2], so2,
                       fmaf(wN[dr][2], pn[2], Fc[dr][2]))));
            u[dr][3] = fmaf(wE[dr][3], hEv[dr],
                       fmaf(wW[dr][3], o2,
                       fmaf(wS[dr][3], so3,
                       fmaf(wN[dr][3], pn[3], Fc[dr][3]))));
            pn[0] = o0; pn[1] = o1; pn[2] = o2; pn[3] = o3;
        }
    }

    // ---- store valid region [8,56)^2 (inner 12x12 threads) ----
    if (pr >= 2 && pr < 14 && pc >= 2 && pc < 14) {
        const int gx = X0 + C0;                       // multiple of 4, >= 0
        if (LAST) {
            float* oB = udst + (size_t)b * IMG_P;     // stride 1022 (8B-aligned rows)
            #pragma unroll
            for (int dr = 0; dr < 4; ++dr) {
                const int gy = Y0 + R0 + dr;
                if (gy < Ni) {
                    float* p = oB + (size_t)gy * Ni + gx;
                    if (gx + 1 < Ni) *(float2*)(p)     = make_float2(u[dr][0], u[dr][1]);
                    if (gx + 3 < Ni) *(float2*)(p + 2) = make_float2(u[dr][2], u[dr][3]);
                }
            }
        } else {
            float* oB = udst + (size_t)b * IMG_W;     // stride 1024, write pads as 0
            #pragma unroll
            for (int dr = 0; dr < 4; ++dr) {
                const int gy = Y0 + R0 + dr;
                if (gy < 1024 && gx <= 1020)
                    *(float4*)(oB + (size_t)gy * WSTR + gx)
                        = make_float4(u[dr][0], u[dr][1], u[dr][2], u[dr][3]);
            }
        }
    }
}

extern "C" void kernel_launch(void* const* d_in, const int* in_sizes, int n_in,
                              void* d_out, int out_size, void* d_ws, size_t ws_size,
                              hipStream_t stream)
{
    const float* pre = (const float*)d_in[0];
    const float* f   = (const float*)d_in[1];
    const float* kap = (const float*)d_in[2];
    float* out = (float*)d_out;
    float* ws  = (float*)d_ws;                 // needs 8*1024*1024*4 = 33.6 MB

    dim3 blk(256, 1, 1);
    dim3 grd((Ni + TOUT - 1) / TOUT, (Ni + TOUT - 1) / TOUT, 8);   // 22 x 22 x 8

    jac_fused8<true,  false><<<grd, blk, 0, stream>>>(pre, ws,  kap, f);
    jac_fused8<false, true ><<<grd, blk, 0, stream>>>(ws,  out, kap, f);
}

// Round 4
// 399.480 us; speedup vs baseline: 1.9777x; 1.9777x over previous
//
#include <hip/hip_runtime.h>

// Register-resident fused-8 Jacobi. Thread = fixed 4x4 patch in VGPRs; weights
// (iteration-invariant, kappa-derived) precomputed once; per-step halo exchange
// via double-buffered LDS edge buffers (1 barrier/step, conflict-free b128).
// No per-step masking: trapezoid validity + zeroed out-of-domain weights.
// __launch_bounds__(256,2): 256-reg budget so ~150 live regs NEVER spill to
// scratch ((256,4) spilled -> 758 MB/dispatch scratch writes, R3 post-mortem).

namespace {
constexpr int    G    = 1024, Ni = 1022;
constexpr int    TOUT = 48, HALO = 8;
constexpr int    KSTR = 68;                       // kT row stride (16B-aligned rows)
constexpr size_t IMG_K = (size_t)G * G;
constexpr size_t IMG_P = (size_t)Ni * Ni;
constexpr size_t WSTR  = 1024;
constexpr size_t IMG_W = (size_t)1024 * 1024;     // ws image incl. zero pad rows/cols
constexpr float  H2 = (float)(1.0 / (1023.0 * 1023.0));
// LDS: setup kT[66*68]=4488 | fT[64*64]=4096  (8584 floats total)
// main: exchange dbuf = 2 * 4096 floats, overlays setup region. 34,336 B.
}

__device__ __forceinline__ float frcp(float x) { return __builtin_amdgcn_rcpf(x); }

template<bool FIRST, bool LAST>
__global__ __launch_bounds__(256, 2)
void jac_fused8(const float* __restrict__ usrc, float* __restrict__ udst,
                const float* __restrict__ kap,  const float* __restrict__ fin)
{
    __shared__ float lds[8584];
    float* kT = lds;                 // 66 rows x 68 stride
    float* fT = lds + 4488;          // 64 x 64

    const int tid = threadIdx.x;
    const int pr = tid >> 4, pc = tid & 15;
    const int R0 = pr * 4, C0 = pc * 4;
    const int bx = blockIdx.x, by = blockIdx.y, b = blockIdx.z;
    const int X0 = bx * TOUT - HALO, Y0 = by * TOUT - HALO;

    const float* kB = kap + (size_t)b * IMG_K;
    const float* fB = fin + (size_t)b * IMG_K;

    // ---- u patch into registers ----
    float u[4][4];
    if (FIRST) {
        const float* uS = usrc + (size_t)b * IMG_P;       // pre, stride 1022
        #pragma unroll
        for (int dr = 0; dr < 4; ++dr) {
            const int gy = Y0 + R0 + dr;
            #pragma unroll
            for (int dc = 0; dc < 4; ++dc) {
                const int gx = X0 + C0 + dc;
                u[dr][dc] = ((unsigned)gy < (unsigned)Ni && (unsigned)gx < (unsigned)Ni)
                          ? uS[(size_t)gy * Ni + gx] : 0.0f;
            }
        }
    } else {
        const float* uS = usrc + (size_t)b * IMG_W;       // ws, stride 1024, padded
        const int gx = X0 + C0;
        #pragma unroll
        for (int dr = 0; dr < 4; ++dr) {
            const int gy = Y0 + R0 + dr;
            float4 v = make_float4(0.f, 0.f, 0.f, 0.f);
            if ((unsigned)gy < 1024u && (unsigned)gx <= 1020u)
                v = *(const float4*)(uS + (size_t)gy * WSTR + gx);
            u[dr][0] = v.x; u[dr][1] = v.y; u[dr][2] = v.z; u[dr][3] = v.w;
        }
    }

    // ---- stage kappa tile (grid [Y0,Y0+66) x [X0,X0+66), clipped) ----
    for (int lin = tid; lin < 66 * 66; lin += 256) {
        const int r = lin / 66, c = lin - r * 66;
        const int gy = Y0 + r, gx = X0 + c;
        float v = 0.0f;
        if ((unsigned)gy < (unsigned)G && (unsigned)gx < (unsigned)G)
            v = kB[(size_t)gy * G + gx];
        kT[r * KSTR + c] = v;
    }
    // ---- stage f tile (f grid (Y0+r+1, X0+c+1), clipped) ----
    #pragma unroll
    for (int k = 0; k < 16; ++k) {
        const int lin = tid + k * 256;
        const int r = lin >> 6, c = lin & 63;
        const int gy = Y0 + r + 1, gx = X0 + c + 1;
        float v = 0.0f;
        if ((unsigned)gy < (unsigned)G && (unsigned)gx < (unsigned)G)
            v = fB[(size_t)gy * G + gx];
        fT[r * 64 + c] = v;
    }
    __syncthreads();

    // ---- iteration-invariant weights (zeroed outside domain) ----
    float wN[4][4], wS[4][4], wW[4][4], wE[4][4], Fc[4][4];
    {
        float ka[6], kb2[6], kc2[6];
        auto loadK = [&](int r, float* dst) {
            const float4 q = *(const float4*)(kT + r * KSTR + C0);
            const float2 p = *(const float2*)(kT + r * KSTR + C0 + 4);
            dst[0] = q.x; dst[1] = q.y; dst[2] = q.z; dst[3] = q.w; dst[4] = p.x; dst[5] = p.y;
        };
        loadK(R0 + 0, ka);
        loadK(R0 + 1, kb2);
        #pragma unroll
        for (int dr = 0; dr < 4; ++dr) {
            loadK(R0 + dr + 2, kc2);
            const float4 fr = *(const float4*)(fT + (R0 + dr) * 64 + C0);
            const float frow[4] = {fr.x, fr.y, fr.z, fr.w};
            const int gy = Y0 + R0 + dr;
            #pragma unroll
            for (int dc = 0; dc < 4; ++dc) {
                const float kn = ka[dc + 1], kc = kb2[dc + 1], kw = kb2[dc],
                            ke = kb2[dc + 2], ks = kc2[dc + 1];
                const float y3  = 2.0f * kc + 0.5f * (kn + ks + kw + ke);
                const float inv = frcp(y3);
                const int gx = X0 + C0 + dc;
                const bool dv = ((unsigned)gy < (unsigned)Ni) && ((unsigned)gx < (unsigned)Ni);
                wN[dr][dc] = dv ? 0.5f * (kc + kn) * inv : 0.0f;
                wS[dr][dc] = dv ? 0.5f * (kc + ks) * inv : 0.0f;
                wW[dr][dc] = dv ? 0.5f * (kc + kw) * inv : 0.0f;
                wE[dr][dc] = dv ? 0.5f * (kc + ke) * inv : 0.0f;
                Fc[dr][dc] = dv ? frow[dc] * H2 * inv : 0.0f;
            }
            #pragma unroll
            for (int i = 0; i < 6; ++i) { ka[i] = kb2[i]; kb2[i] = kc2[i]; }
        }
    }
    __syncthreads();   // kT/fT dead; exchange buffers overlay them

    // ---- 8 Jacobi steps, halo via dbuf LDS edge exchange ----
    const int tN = (tid >= 16)  ? tid - 16 : 0;
    const int tS = (tid < 240)  ? tid + 16 : 255;
    const int tW = (tid > 0)    ? tid - 1  : 0;
    const int tE = (tid < 255)  ? tid + 1  : 255;

    #pragma unroll
    for (int t = 1; t <= 8; ++t) {
        float* ex   = lds + ((t & 1) ? 0 : 4096);
        float* rowT = ex, *rowB = ex + 1024, *colL = ex + 2048, *colR = ex + 3072;
        *(float4*)(rowT + tid * 4) = make_float4(u[0][0], u[0][1], u[0][2], u[0][3]);
        *(float4*)(rowB + tid * 4) = make_float4(u[3][0], u[3][1], u[3][2], u[3][3]);
        *(float4*)(colL + tid * 4) = make_float4(u[0][0], u[1][0], u[2][0], u[3][0]);
        *(float4*)(colR + tid * 4) = make_float4(u[0][3], u[1][3], u[2][3], u[3][3]);
        __syncthreads();
        const float4 hN = *(const float4*)(rowB + tN * 4);
        const float4 hS = *(const float4*)(rowT + tS * 4);
        const float4 hW = *(const float4*)(colR + tW * 4);
        const float4 hE = *(const float4*)(colL + tE * 4);
        float pn[4]        = {hN.x, hN.y, hN.z, hN.w};
        const float hWv[4] = {hW.x, hW.y, hW.z, hW.w};
        const float hEv[4] = {hE.x, hE.y, hE.z, hE.w};
        #pragma unroll
        for (int dr = 0; dr < 4; ++dr) {
            float so0, so1, so2, so3;
            if (dr < 3) { so0 = u[dr+1][0]; so1 = u[dr+1][1]; so2 = u[dr+1][2]; so3 = u[dr+1][3]; }
            else        { so0 = hS.x;       so1 = hS.y;       so2 = hS.z;       so3 = hS.w;       }
            const float o0 = u[dr][0], o1 = u[dr][1], o2 = u[dr][2], o3 = u[dr][3];
            u[dr][0] = fmaf(wE[dr][0], o1,
                       fmaf(wW[dr][0], hWv[dr],
                       fmaf(wS[dr][0], so0,
                       fmaf(wN[dr][0], pn[0], Fc[dr][0]))));
            u[dr][1] = fmaf(wE[dr][1], o2,
                       fmaf(wW[dr][1], o0,
                       fmaf(wS[dr][1], so1,
                       fmaf(wN[dr][1], pn[1], Fc[dr][1]))));
            u[dr][2] = fmaf(wE[dr][2], o3,
                       fmaf(wW[dr][2], o1,
                       fmaf(wS[dr][2], so2,
                       fmaf(wN[dr][2], pn[2], Fc[dr][2]))));
            u[dr][3] = fmaf(wE[dr][3], hEv[dr],
                       fmaf(wW[dr][3], o2,
                       fmaf(wS[dr][3], so3,
                       fmaf(wN[dr][3], pn[3], Fc[dr][3]))));
            pn[0] = o0; pn[1] = o1; pn[2] = o2; pn[3] = o3;
        }
    }

    // ---- store valid region [8,56)^2 (inner 12x12 threads) ----
    if (pr >= 2 && pr < 14 && pc >= 2 && pc < 14) {
        const int gx = X0 + C0;                       // multiple of 4, >= 0
        if (LAST) {
            float* oB = udst + (size_t)b * IMG_P;     // stride 1022 (8B-aligned rows)
            #pragma unroll
            for (int dr = 0; dr < 4; ++dr) {
                const int gy = Y0 + R0 + dr;
                if (gy < Ni) {
                    float* p = oB + (size_t)gy * Ni + gx;
                    if (gx + 1 < Ni) *(float2*)(p)     = make_float2(u[dr][0], u[dr][1]);
                    if (gx + 3 < Ni) *(float2*)(p + 2) = make_float2(u[dr][2], u[dr][3]);
                }
            }
        } else {
            float* oB = udst + (size_t)b * IMG_W;     // stride 1024, write pads as 0
            #pragma unroll
            for (int dr = 0; dr < 4; ++dr) {
                const int gy = Y0 + R0 + dr;
                if (gy < 1024 && gx <= 1020)
                    *(float4*)(oB + (size_t)gy * WSTR + gx)
                        = make_float4(u[dr][0], u[dr][1], u[dr][2], u[dr][3]);
            }
        }
    }
}

extern "C" void kernel_launch(void* const* d_in, const int* in_sizes, int n_in,
                              void* d_out, int out_size, void* d_ws, size_t ws_size,
                              hipStream_t stream)
{
    const float* pre = (const float*)d_in[0];
    const float* f   = (const float*)d_in[1];
    const float* kap = (const float*)d_in[2];
    float* out = (float*)d_out;
    float* ws  = (float*)d_ws;                 // needs 8*1024*1024*4 = 33.6 MB

    dim3 blk(256, 1, 1);
    dim3 grd((Ni + TOUT - 1) / TOUT, (Ni + TOUT - 1) / TOUT, 8);   // 22 x 22 x 8

    jac_fused8<true,  false><<<grd, blk, 0, stream>>>(pre, ws,  kap, f);
    jac_fused8<false, true ><<<grd, blk, 0, stream>>>(ws,  out, kap, f);
}

// Round 5
// 349.969 us; speedup vs baseline: 2.2575x; 1.1415x over previous
//
#include <hip/hip_runtime.h>

// Register-resident fused-8 Jacobi. Thread = fixed 4x4 patch in VGPRs; weights
// (iteration-invariant) precomputed once; per-step halo exchange via
// double-buffered LDS edge buffers. Setup staging via global_load_lds DMA
// (interior blocks): kappa = 66x68 tile (1122 x 16B chunks), f = 64x68
// (1088 chunks), wave-uniform LDS base + lane*16 layout honored.
// __launch_bounds__(256,3): ~170-reg budget, no spills (R3: (256,4) spilled
// 758MB/dispatch; R4: (256,2) left occupancy at 8 waves/CU -> latency-bound).

namespace {
constexpr int    G    = 1024, Ni = 1022;
constexpr int    TOUT = 48, HALO = 8;
constexpr int    KSTR = 68;                       // kT/fT row stride (floats)
constexpr size_t IMG_K = (size_t)G * G;
constexpr size_t IMG_P = (size_t)Ni * Ni;
constexpr size_t WSTR  = 1024;
constexpr size_t IMG_W = (size_t)1024 * 1024;
constexpr float  H2 = (float)(1.0 / (1023.0 * 1023.0));
// LDS: kT[66*68]=4488 | fT[64*68]=4352 -> 8840 floats = 35,360 B.
// Main-loop exchange dbuf (2*4096 floats) overlays [0,8192).
}

__device__ __forceinline__ float frcp(float x) { return __builtin_amdgcn_rcpf(x); }

__device__ __forceinline__ void dma16(const float* g, float* l) {
    __builtin_amdgcn_global_load_lds(
        (const __attribute__((address_space(1))) void*)g,
        (__attribute__((address_space(3))) void*)l, 16, 0, 0);
}

template<bool FIRST, bool LAST>
__global__ __launch_bounds__(256, 3)
void jac_fused8(const float* __restrict__ usrc, float* __restrict__ udst,
                const float* __restrict__ kap,  const float* __restrict__ fin)
{
    __shared__ __align__(16) float lds[8840];
    float* kT = lds;                 // 66 rows x 68 stride, col c <-> grid X0+c
    float* fT = lds + 4488;          // 64 rows x 68 stride, col c <-> grid X0+c, row r <-> grid Y0+1+r

    const int tid = threadIdx.x;
    const int pr = tid >> 4, pc = tid & 15;
    const int R0 = pr * 4, C0 = pc * 4;
    const int bx = blockIdx.x, by = blockIdx.y, b = blockIdx.z;
    const int X0 = bx * TOUT - HALO, Y0 = by * TOUT - HALO;

    const float* kB = kap + (size_t)b * IMG_K;
    const float* fB = fin + (size_t)b * IMG_K;

    // ---- u patch into registers (issue first; independent of staging) ----
    float u[4][4];
    if (FIRST) {
        const float* uS = usrc + (size_t)b * IMG_P;       // pre, stride 1022
        #pragma unroll
        for (int dr = 0; dr < 4; ++dr) {
            const int gy = Y0 + R0 + dr;
            #pragma unroll
            for (int dc = 0; dc < 4; ++dc) {
                const int gx = X0 + C0 + dc;
                u[dr][dc] = ((unsigned)gy < (unsigned)Ni && (unsigned)gx < (unsigned)Ni)
                          ? uS[(size_t)gy * Ni + gx] : 0.0f;
            }
        }
    } else {
        const float* uS = usrc + (size_t)b * IMG_W;       // ws, stride 1024, padded
        const int gx = X0 + C0;
        #pragma unroll
        for (int dr = 0; dr < 4; ++dr) {
            const int gy = Y0 + R0 + dr;
            float4 v = make_float4(0.f, 0.f, 0.f, 0.f);
            if ((unsigned)gy < 1024u && (unsigned)gx <= 1020u)
                v = *(const float4*)(uS + (size_t)gy * WSTR + gx);
            u[dr][0] = v.x; u[dr][1] = v.y; u[dr][2] = v.z; u[dr][3] = v.w;
        }
    }

    // ---- stage kappa + f tiles ----
    const bool fast = (bx >= 1) && (bx <= 20) && (by >= 1) && (by <= 20);
    if (fast) {
        // kappa: rows Y0..Y0+65, cols X0..X0+67 (all in-bounds). 1122 chunks.
        const float* gk = kB + (size_t)Y0 * G + X0;
        #pragma unroll
        for (int it = 0; it < 5; ++it) {
            const int idx = it * 256 + tid;
            if (it < 4 || idx < 1122) {
                const int r = idx / 17, c4 = idx - r * 17;
                dma16(gk + (size_t)r * G + c4 * 4,
                      kT + (size_t)(it * 256 + (tid & 192)) * 4);
            }
        }
        // f: rows Y0+1..Y0+64, cols X0..X0+67. 1088 chunks.
        const float* gf = fB + (size_t)(Y0 + 1) * G + X0;
        #pragma unroll
        for (int it = 0; it < 5; ++it) {
            const int idx = it * 256 + tid;
            if (it < 4 || idx < 1088) {
                const int r = idx / 17, c4 = idx - r * 17;
                dma16(gf + (size_t)r * G + c4 * 4,
                      fT + (size_t)(it * 256 + (tid & 192)) * 4);
            }
        }
    } else {
        // boundary blocks: scalar clipped staging
        for (int lin = tid; lin < 66 * 68; lin += 256) {
            const int r = lin / 68, c = lin - r * 68;
            const int gy = Y0 + r, gx = X0 + c;
            float v = 0.0f;
            if ((unsigned)gy < (unsigned)G && (unsigned)gx < (unsigned)G)
                v = kB[(size_t)gy * G + gx];
            kT[lin] = v;
        }
        for (int lin = tid; lin < 64 * 65; lin += 256) {
            const int r = lin / 65, c = lin - r * 65;
            const int gy = Y0 + 1 + r, gx = X0 + c;
            float v = 0.0f;
            if ((unsigned)gy < (unsigned)G && (unsigned)gx < (unsigned)G)
                v = fB[(size_t)gy * G + gx];
            fT[r * KSTR + c] = v;
        }
    }
    __syncthreads();   // drains DMA (vmcnt) + LDS stores

    // ---- iteration-invariant weights (zeroed outside domain) ----
    float wN[4][4], wS[4][4], wW[4][4], wE[4][4], Fc[4][4];
    {
        float ka[6], kb2[6], kc2[6];
        auto loadK = [&](int r, float* dst) {
            const float4 q = *(const float4*)(kT + r * KSTR + C0);
            const float2 p = *(const float2*)(kT + r * KSTR + C0 + 4);
            dst[0] = q.x; dst[1] = q.y; dst[2] = q.z; dst[3] = q.w; dst[4] = p.x; dst[5] = p.y;
        };
        loadK(R0 + 0, ka);
        loadK(R0 + 1, kb2);
        #pragma unroll
        for (int dr = 0; dr < 4; ++dr) {
            loadK(R0 + dr + 2, kc2);
            // f row: cols C0+1..C0+4 from two aligned b128s
            const float4 q0 = *(const float4*)(fT + (R0 + dr) * KSTR + C0);
            const float4 q1 = *(const float4*)(fT + (R0 + dr) * KSTR + C0 + 4);
            const float frow[4] = {q0.y, q0.z, q0.w, q1.x};
            const int gy = Y0 + R0 + dr;
            #pragma unroll
            for (int dc = 0; dc < 4; ++dc) {
                const float kn = ka[dc + 1], kc = kb2[dc + 1], kw = kb2[dc],
                            ke = kb2[dc + 2], ks = kc2[dc + 1];
                const float y3  = 2.0f * kc + 0.5f * (kn + ks + kw + ke);
                const float inv = frcp(y3);
                const int gx = X0 + C0 + dc;
                const bool dv = ((unsigned)gy < (unsigned)Ni) && ((unsigned)gx < (unsigned)Ni);
                wN[dr][dc] = dv ? 0.5f * (kc + kn) * inv : 0.0f;
                wS[dr][dc] = dv ? 0.5f * (kc + ks) * inv : 0.0f;
                wW[dr][dc] = dv ? 0.5f * (kc + kw) * inv : 0.0f;
                wE[dr][dc] = dv ? 0.5f * (kc + ke) * inv : 0.0f;
                Fc[dr][dc] = dv ? frow[dc] * H2 * inv : 0.0f;
            }
            #pragma unroll
            for (int i = 0; i < 6; ++i) { ka[i] = kb2[i]; kb2[i] = kc2[i]; }
        }
    }
    __syncthreads();   // kT/fT dead; exchange buffers overlay them

    // ---- 8 Jacobi steps, halo via dbuf LDS edge exchange ----
    const int tN = (tid >= 16)  ? tid - 16 : 0;
    const int tS = (tid < 240)  ? tid + 16 : 255;
    const int tW = (tid > 0)    ? tid - 1  : 0;
    const int tE = (tid < 255)  ? tid + 1  : 255;

    #pragma unroll
    for (int t = 1; t <= 8; ++t) {
        float* ex   = lds + ((t & 1) ? 0 : 4096);
        float* rowT = ex, *rowB = ex + 1024, *colL = ex + 2048, *colR = ex + 3072;
        *(float4*)(rowT + tid * 4) = make_float4(u[0][0], u[0][1], u[0][2], u[0][3]);
        *(float4*)(rowB + tid * 4) = make_float4(u[3][0], u[3][1], u[3][2], u[3][3]);
        *(float4*)(colL + tid * 4) = make_float4(u[0][0], u[1][0], u[2][0], u[3][0]);
        *(float4*)(colR + tid * 4) = make_float4(u[0][3], u[1][3], u[2][3], u[3][3]);
        __syncthreads();
        const float4 hN = *(const float4*)(rowB + tN * 4);
        const float4 hS = *(const float4*)(rowT + tS * 4);
        const float4 hW = *(const float4*)(colR + tW * 4);
        const float4 hE = *(const float4*)(colL + tE * 4);
        float pn[4]        = {hN.x, hN.y, hN.z, hN.w};
        const float hWv[4] = {hW.x, hW.y, hW.z, hW.w};
        const float hEv[4] = {hE.x, hE.y, hE.z, hE.w};
        #pragma unroll
        for (int dr = 0; dr < 4; ++dr) {
            float so0, so1, so2, so3;
            if (dr < 3) { so0 = u[dr+1][0]; so1 = u[dr+1][1]; so2 = u[dr+1][2]; so3 = u[dr+1][3]; }
            else        { so0 = hS.x;       so1 = hS.y;       so2 = hS.z;       so3 = hS.w;       }
            const float o0 = u[dr][0], o1 = u[dr][1], o2 = u[dr][2], o3 = u[dr][3];
            u[dr][0] = fmaf(wE[dr][0], o1,
                       fmaf(wW[dr][0], hWv[dr],
                       fmaf(wS[dr][0], so0,
                       fmaf(wN[dr][0], pn[0], Fc[dr][0]))));
            u[dr][1] = fmaf(wE[dr][1], o2,
                       fmaf(wW[dr][1], o0,
                       fmaf(wS[dr][1], so1,
                       fmaf(wN[dr][1], pn[1], Fc[dr][1]))));
            u[dr][2] = fmaf(wE[dr][2], o3,
                       fmaf(wW[dr][2], o1,
                       fmaf(wS[dr][2], so2,
                       fmaf(wN[dr][2], pn[2], Fc[dr][2]))));
            u[dr][3] = fmaf(wE[dr][3], hEv[dr],
                       fmaf(wW[dr][3], o2,
                       fmaf(wS[dr][3], so3,
                       fmaf(wN[dr][3], pn[3], Fc[dr][3]))));
            pn[0] = o0; pn[1] = o1; pn[2] = o2; pn[3] = o3;
        }
    }

    // ---- store valid region [8,56)^2 (inner 12x12 threads) ----
    if (pr >= 2 && pr < 14 && pc >= 2 && pc < 14) {
        const int gx = X0 + C0;                       // multiple of 4, >= 0
        if (LAST) {
            float* oB = udst + (size_t)b * IMG_P;     // stride 1022
            #pragma unroll
            for (int dr = 0; dr < 4; ++dr) {
                const int gy = Y0 + R0 + dr;
                if (gy < Ni) {
                    float* p = oB + (size_t)gy * Ni + gx;
                    if (gx + 1 < Ni) *(float2*)(p)     = make_float2(u[dr][0], u[dr][1]);
                    if (gx + 3 < Ni) *(float2*)(p + 2) = make_float2(u[dr][2], u[dr][3]);
                }
            }
        } else {
            float* oB = udst + (size_t)b * IMG_W;     // stride 1024, zero pads
            #pragma unroll
            for (int dr = 0; dr < 4; ++dr) {
                const int gy = Y0 + R0 + dr;
                if (gy < 1024 && gx <= 1020)
                    *(float4*)(oB + (size_t)gy * WSTR + gx)
                        = make_float4(u[dr][0], u[dr][1], u[dr][2], u[dr][3]);
            }
        }
    }
}

extern "C" void kernel_launch(void* const* d_in, const int* in_sizes, int n_in,
                              void* d_out, int out_size, void* d_ws, size_t ws_size,
                              hipStream_t stream)
{
    const float* pre = (const float*)d_in[0];
    const float* f   = (const float*)d_in[1];
    const float* kap = (const float*)d_in[2];
    float* out = (float*)d_out;
    float* ws  = (float*)d_ws;                 // needs 8*1024*1024*4 = 33.6 MB

    dim3 blk(256, 1, 1);
    dim3 grd((Ni + TOUT - 1) / TOUT, (Ni + TOUT - 1) / TOUT, 8);   // 22 x 22 x 8

    jac_fused8<true,  false><<<grd, blk, 0, stream>>>(pre, ws,  kap, f);
    jac_fused8<false, true ><<<grd, blk, 0, stream>>>(ws,  out, kap, f);
}

// Round 6
// 298.547 us; speedup vs baseline: 2.6464x; 1.1722x over previous
//
#include <hip/hip_runtime.h>

// Register-resident fused-8 Jacobi, v3.
//  - thread = fixed 4x4 patch; weights iteration-invariant in regs.
//  - contraction wN+wS+wW+wE==1 -> wE eliminated; state = 80 floats
//    (u16 + wN/wS/wW 48 + Fc16) so it fits arch VGPRs at (256,3)
//    (R5: 96 floats vs VGPR_Count=84 -> AGPR/scratch round-trips, WRITE 150-235MB).
//  - W/E halo via DPP wave_shr1/wave_shl1 (lane+-1); N/S via dbuf LDS rows.
//  - f loaded straight to registers (no LDS staging); kappa via global_load_lds DMA.
//  - domain-boundary zeros: separable row/col float masks, boundary blocks only.

namespace {
constexpr int    G    = 1024, Ni = 1022;
constexpr int    TOUT = 48, HALO = 8;
constexpr int    KSTR = 68;                       // kT row stride (floats)
constexpr size_t IMG_K = (size_t)G * G;
constexpr size_t IMG_P = (size_t)Ni * Ni;
constexpr size_t WSTR  = 1024;
constexpr size_t IMG_W = (size_t)1024 * 1024;
constexpr float  H2 = (float)(1.0 / (1023.0 * 1023.0));
// LDS: kT[66*68]=4488 floats = 17,952 B; main-loop dbuf (2*2048) overlays it.
}

__device__ __forceinline__ float frcp(float x) { return __builtin_amdgcn_rcpf(x); }

__device__ __forceinline__ void dma16(const float* g, float* l) {
    __builtin_amdgcn_global_load_lds(
        (const __attribute__((address_space(1))) void*)g,
        (__attribute__((address_space(3))) void*)l, 16, 0, 0);
}

// lane l <- lane l-1 (wave_shr1); shifted-in lane gets 0 (bound_ctrl)
__device__ __forceinline__ float lane_shr1(float x) {
    return __builtin_bit_cast(float,
        __builtin_amdgcn_update_dpp(0, __builtin_bit_cast(int, x), 0x138, 0xF, 0xF, true));
}
// lane l <- lane l+1 (wave_shl1)
__device__ __forceinline__ float lane_shl1(float x) {
    return __builtin_bit_cast(float,
        __builtin_amdgcn_update_dpp(0, __builtin_bit_cast(int, x), 0x130, 0xF, 0xF, true));
}

template<bool FIRST, bool LAST>
__global__ __launch_bounds__(256, 3)
void jac_fused8(const float* __restrict__ usrc, float* __restrict__ udst,
                const float* __restrict__ kap,  const float* __restrict__ fin)
{
    __shared__ __align__(16) float lds[4488];
    float* kT = lds;                               // 66 rows x 68 stride

    const int tid = threadIdx.x;
    const int pr = tid >> 4, pc = tid & 15;
    const int R0 = pr * 4, C0 = pc * 4;
    const int bx = blockIdx.x, by = blockIdx.y, b = blockIdx.z;
    const int X0 = bx * TOUT - HALO, Y0 = by * TOUT - HALO;

    const float* kB = kap + (size_t)b * IMG_K;
    const float* fB = fin + (size_t)b * IMG_K;
    const bool fast = (bx >= 1) && (bx <= 20) && (by >= 1) && (by <= 20);

    // ---- kappa staging (issue DMA first so it's in flight) ----
    if (fast) {
        const float* gk = kB + (size_t)Y0 * G + X0;   // rows Y0..Y0+65 all in-bounds
        #pragma unroll
        for (int it = 0; it < 5; ++it) {
            const int idx = it * 256 + tid;           // chunk id, 1122 total (17/row)
            if (it < 4 || idx < 1122) {
                const int r = idx / 17, c4 = idx - r * 17;
                dma16(gk + (size_t)r * G + c4 * 4,
                      kT + (size_t)(it * 256 + (tid & 192)) * 4);
            }
        }
    } else {
        for (int lin = tid; lin < 66 * 68; lin += 256) {
            const int r = lin / 68, c = lin - r * 68;
            const int gy = Y0 + r, gx = X0 + c;
            float v = 0.0f;
            if ((unsigned)gy < (unsigned)G && (unsigned)gx < (unsigned)G)
                v = kB[(size_t)gy * G + gx];
            kT[lin] = v;
        }
    }

    // ---- u patch into registers ----
    float u[4][4];
    if (FIRST) {
        const float* uS = usrc + (size_t)b * IMG_P;   // pre, stride 1022
        #pragma unroll
        for (int dr = 0; dr < 4; ++dr) {
            const int gy = Y0 + R0 + dr;
            #pragma unroll
            for (int dc = 0; dc < 4; ++dc) {
                const int gx = X0 + C0 + dc;
                u[dr][dc] = ((unsigned)gy < (unsigned)Ni && (unsigned)gx < (unsigned)Ni)
                          ? uS[(size_t)gy * Ni + gx] : 0.0f;
            }
        }
    } else {
        const float* uS = usrc + (size_t)b * IMG_W;   // ws, stride 1024, zero-padded
        const int gx = X0 + C0;
        #pragma unroll
        for (int dr = 0; dr < 4; ++dr) {
            const int gy = Y0 + R0 + dr;
            float4 v = make_float4(0.f, 0.f, 0.f, 0.f);
            if ((unsigned)gy < 1024u && (unsigned)gx <= 1020u)
                v = *(const float4*)(uS + (size_t)gy * WSTR + gx);
            u[dr][0] = v.x; u[dr][1] = v.y; u[dr][2] = v.z; u[dr][3] = v.w;
        }
    }

    // ---- f direct to registers (grid rows Y0+1+R0+dr, cols fx0..fx0+7) ----
    float4 fq0[4], fq1[4];
    {
        const int fx0 = X0 + C0;
        #pragma unroll
        for (int dr = 0; dr < 4; ++dr) {
            const int gy = Y0 + 1 + R0 + dr;
            fq0[dr] = make_float4(0.f, 0.f, 0.f, 0.f);
            fq1[dr] = make_float4(0.f, 0.f, 0.f, 0.f);
            if ((unsigned)gy < (unsigned)G) {
                const float* fr = fB + (size_t)gy * G;
                if ((unsigned)fx0       <= (unsigned)(G - 4)) fq0[dr] = *(const float4*)(fr + fx0);
                if ((unsigned)(fx0 + 4) <= (unsigned)(G - 4)) fq1[dr] = *(const float4*)(fr + fx0 + 4);
            }
        }
    }
    __syncthreads();   // drains kappa DMA (vmcnt) before kT reads

    // ---- iteration-invariant weights; wE implicit (== 1 - wN - wS - wW) ----
    float wN[4][4], wS[4][4], wW[4][4], Fc[4][4];
    float rm[4], cm[4];                                // boundary masks (0/1)
    {
        float ka[6], kb2[6], kc2[6];
        auto loadK = [&](int r, float* dst) {
            const float4 q = *(const float4*)(kT + r * KSTR + C0);
            const float2 p = *(const float2*)(kT + r * KSTR + C0 + 4);
            dst[0] = q.x; dst[1] = q.y; dst[2] = q.z; dst[3] = q.w; dst[4] = p.x; dst[5] = p.y;
        };
        loadK(R0 + 0, ka);
        loadK(R0 + 1, kb2);
        #pragma unroll
        for (int dr = 0; dr < 4; ++dr) {
            loadK(R0 + dr + 2, kc2);
            const float frow[4] = {fq0[dr].y, fq0[dr].z, fq0[dr].w, fq1[dr].x};
            const int gy = Y0 + R0 + dr;
            rm[dr] = ((unsigned)gy < (unsigned)Ni) ? 1.0f : 0.0f;
            #pragma unroll
            for (int dc = 0; dc < 4; ++dc) {
                const float kn = ka[dc + 1], kc = kb2[dc + 1], kw = kb2[dc],
                            ke = kb2[dc + 2], ks = kc2[dc + 1];
                const float y3  = 2.0f * kc + 0.5f * (kn + ks + kw + ke);
                const float inv = frcp(y3);
                const int gx = X0 + C0 + dc;
                const bool dv = ((unsigned)gy < (unsigned)Ni) && ((unsigned)gx < (unsigned)Ni);
                if (dr == 0) cm[dc] = ((unsigned)gx < (unsigned)Ni) ? 1.0f : 0.0f;
                wN[dr][dc] = dv ? 0.5f * (kc + kn) * inv : 0.0f;
                wS[dr][dc] = dv ? 0.5f * (kc + ks) * inv : 0.0f;
                wW[dr][dc] = dv ? 0.5f * (kc + kw) * inv : 0.0f;
                Fc[dr][dc] = dv ? frow[dc] * H2 * inv : 0.0f;
            }
            #pragma unroll
            for (int i = 0; i < 6; ++i) { ka[i] = kb2[i]; kb2[i] = kc2[i]; }
        }
    }
    __syncthreads();   // kT dead; exchange dbuf overlays it

    // ---- 8 steps; N/S via dbuf LDS rows, W/E via DPP lane+-1 ----
    const int tN = (tid >= 16)  ? tid - 16 : 0;
    const int tS = (tid < 240)  ? tid + 16 : 255;

    auto run = [&](bool masked) {
        #pragma unroll
        for (int t = 1; t <= 8; ++t) {
            float* ex   = lds + ((t & 1) ? 0 : 2048);
            float* rowT = ex; float* rowB = ex + 1024;
            *(float4*)(rowT + tid * 4) = make_float4(u[0][0], u[0][1], u[0][2], u[0][3]);
            *(float4*)(rowB + tid * 4) = make_float4(u[3][0], u[3][1], u[3][2], u[3][3]);
            __syncthreads();
            const float4 hN = *(const float4*)(rowB + tN * 4);
            const float4 hS = *(const float4*)(rowT + tS * 4);
            float pn0 = hN.x, pn1 = hN.y, pn2 = hN.z, pn3 = hN.w;
            #pragma unroll
            for (int dr = 0; dr < 4; ++dr) {
                const float uWh = lane_shr1(u[dr][3]);   // old col3 of lane-1
                const float uEh = lane_shl1(u[dr][0]);   // old col0 of lane+1
                float s0, s1, s2, s3;
                if (dr < 3) { s0 = u[dr+1][0]; s1 = u[dr+1][1]; s2 = u[dr+1][2]; s3 = u[dr+1][3]; }
                else        { s0 = hS.x;       s1 = hS.y;       s2 = hS.z;       s3 = hS.w;       }
                const float o0 = u[dr][0], o1 = u[dr][1], o2 = u[dr][2], o3 = u[dr][3];
                // u' = (Fc + uE) + wN*(uN-uE) + wS*(uS-uE) + wW*(uW-uE)
                float v0 = fmaf(wW[dr][0], uWh - o1,
                           fmaf(wS[dr][0], s0  - o1,
                           fmaf(wN[dr][0], pn0 - o1, Fc[dr][0] + o1)));
                float v1 = fmaf(wW[dr][1], o0  - o2,
                           fmaf(wS[dr][1], s1  - o2,
                           fmaf(wN[dr][1], pn1 - o2, Fc[dr][1] + o2)));
                float v2 = fmaf(wW[dr][2], o1  - o3,
                           fmaf(wS[dr][2], s2  - o3,
                           fmaf(wN[dr][2], pn2 - o3, Fc[dr][2] + o3)));
                float v3 = fmaf(wW[dr][3], o2  - uEh,
                           fmaf(wS[dr][3], s3  - uEh,
                           fmaf(wN[dr][3], pn3 - uEh, Fc[dr][3] + uEh)));
                if (masked) {   // out-of-domain points must stay 0 (implicit wE=1 would leak uE)
                    const float r = rm[dr];
                    v0 *= r * cm[0]; v1 *= r * cm[1]; v2 *= r * cm[2]; v3 *= r * cm[3];
                }
                u[dr][0] = v0; u[dr][1] = v1; u[dr][2] = v2; u[dr][3] = v3;
                pn0 = o0; pn1 = o1; pn2 = o2; pn3 = o3;
            }
        }
    };
    if (fast) run(false); else run(true);   // wave-uniform branch

    // ---- store valid region [8,56)^2 (inner 12x12 threads) ----
    if (pr >= 2 && pr < 14 && pc >= 2 && pc < 14) {
        const int gx = X0 + C0;                       // multiple of 4, >= 0
        if (LAST) {
            float* oB = udst + (size_t)b * IMG_P;     // stride 1022
            #pragma unroll
            for (int dr = 0; dr < 4; ++dr) {
                const int gy = Y0 + R0 + dr;
                if (gy < Ni) {
                    float* p = oB + (size_t)gy * Ni + gx;
                    if (gx + 1 < Ni) *(float2*)(p)     = make_float2(u[dr][0], u[dr][1]);
                    if (gx + 3 < Ni) *(float2*)(p + 2) = make_float2(u[dr][2], u[dr][3]);
                }
            }
        } else {
            float* oB = udst + (size_t)b * IMG_W;     // stride 1024, zero pads intact
            #pragma unroll
            for (int dr = 0; dr < 4; ++dr) {
                const int gy = Y0 + R0 + dr;
                if (gy < 1024 && gx <= 1020)
                    *(float4*)(oB + (size_t)gy * WSTR + gx)
                        = make_float4(u[dr][0], u[dr][1], u[dr][2], u[dr][3]);
            }
        }
    }
}

extern "C" void kernel_launch(void* const* d_in, const int* in_sizes, int n_in,
                              void* d_out, int out_size, void* d_ws, size_t ws_size,
                              hipStream_t stream)
{
    const float* pre = (const float*)d_in[0];
    const float* f   = (const float*)d_in[1];
    const float* kap = (const float*)d_in[2];
    float* out = (float*)d_out;
    float* ws  = (float*)d_ws;                 // needs 8*1024*1024*4 = 33.6 MB

    dim3 blk(256, 1, 1);
    dim3 grd((Ni + TOUT - 1) / TOUT, (Ni + TOUT - 1) / TOUT, 8);   // 22 x 22 x 8

    jac_fused8<true,  false><<<grd, blk, 0, stream>>>(pre, ws,  kap, f);
    jac_fused8<false, true ><<<grd, blk, 0, stream>>>(ws,  out, kap, f);
}